// Round 1
// baseline (125.664 us; speedup 1.0000x reference)
//
#include <hip/hip_runtime.h>

#define B_ 64
#define I_ 1152
#define C_ 32
#define E_ 16
#define D_ 8
#define BC_ 16
#define IC_ 16
#define NIC_ (I_/IC_)   // 72

// Pass kernel: for each (b,i) recompute u_hat[b,i,c,e] = sum_d x[b,i,d]*W[i,c,d,e],
// compute coupling coef (uniform 1/32 or softmax_c of u_hat . vacc), accumulate
// partial s[b,c,e] over the block's i-chunk.
// Thread map (256 thr): c = t&31, eh = (t>>5)&1 (e-half), bq = t>>6 (wave = 4 b's).
template<bool ROUTE>
__global__ __launch_bounds__(256)
void caps_pass(const float* __restrict__ x, const float* __restrict__ W,
               const float* __restrict__ vacc, float* __restrict__ partial)
{
  __shared__ float4 Wl[C_*32];   // W[i] swizzled (quad rotated by c), 16KB
  __shared__ float4 xl[BC_*2];   // x rows for block's 16 b's, 512B

  const int t  = threadIdx.x;
  const int c  = t & 31;
  const int eh = (t >> 5) & 1;
  const int bq = t >> 6;          // 0..3
  const int i0 = blockIdx.x * IC_;
  const int b0 = blockIdx.y * BC_;

  float acc[4][8];
#pragma unroll
  for (int j = 0; j < 4; ++j)
#pragma unroll
    for (int e = 0; e < 8; ++e) acc[j][e] = 0.f;

  float vr[4][8];
  if (ROUTE) {
#pragma unroll
    for (int j = 0; j < 4; ++j) {
      const float4* vp = (const float4*)(vacc + (((size_t)(b0 + bq*4 + j)*C_ + c)*E_ + eh*8));
      float4 a = vp[0], b = vp[1];
      vr[j][0]=a.x; vr[j][1]=a.y; vr[j][2]=a.z; vr[j][3]=a.w;
      vr[j][4]=b.x; vr[j][5]=b.y; vr[j][6]=b.z; vr[j][7]=b.w;
    }
  }

  for (int ii = 0; ii < IC_; ++ii) {
    const int i = i0 + ii;
    __syncthreads();                       // protect prior iter's LDS reads
    // stage W[i]: 1024 float4, coalesced; rotate quad index by c-row to fix banks
    const float4* wg = (const float4*)(W + (size_t)i * (C_*D_*E_));
#pragma unroll
    for (int k = 0; k < 4; ++k) {
      int f  = t + 256*k;                  // 0..1023
      int cc = f >> 5;                     // c row
      int q  = f & 31;                     // quad within row
      Wl[cc*32 + ((q + cc) & 31)] = wg[f];
    }
    // stage x[b0..b0+16][i][0..8)
    if (t < 32) {
      int b = t >> 1, q = t & 1;
      xl[t] = ((const float4*)x)[ ((size_t)(b0 + b) * I_ + i) * 2 + q ];
    }
    __syncthreads();

    float xv[4][8];
#pragma unroll
    for (int j = 0; j < 4; ++j) {
      float4 a = xl[(bq*4 + j)*2 + 0];
      float4 b = xl[(bq*4 + j)*2 + 1];
      xv[j][0]=a.x; xv[j][1]=a.y; xv[j][2]=a.z; xv[j][3]=a.w;
      xv[j][4]=b.x; xv[j][5]=b.y; xv[j][6]=b.z; xv[j][7]=b.w;
    }

    float uh[4][8];
#pragma unroll
    for (int j = 0; j < 4; ++j)
#pragma unroll
      for (int e = 0; e < 8; ++e) uh[j][e] = 0.f;

#pragma unroll
    for (int d = 0; d < D_; ++d) {
#pragma unroll
      for (int qq = 0; qq < 2; ++qq) {
        float4 wv = Wl[c*32 + (((d*4 + eh*2 + qq) + c) & 31)];
        const int eb = qq*4;
#pragma unroll
        for (int j = 0; j < 4; ++j) {
          uh[j][eb+0] = fmaf(xv[j][d], wv.x, uh[j][eb+0]);
          uh[j][eb+1] = fmaf(xv[j][d], wv.y, uh[j][eb+1]);
          uh[j][eb+2] = fmaf(xv[j][d], wv.z, uh[j][eb+2]);
          uh[j][eb+3] = fmaf(xv[j][d], wv.w, uh[j][eb+3]);
        }
      }
    }

    float coef[4];
    if (ROUTE) {
#pragma unroll
      for (int j = 0; j < 4; ++j) {
        float lg = 0.f;
#pragma unroll
        for (int e = 0; e < 8; ++e) lg = fmaf(uh[j][e], vr[j][e], lg);
        lg += __shfl_xor(lg, 32, 64);      // combine e-halves; both halves now identical
        float m = lg;
#pragma unroll
        for (int mk = 16; mk >= 1; mk >>= 1) m = fmaxf(m, __shfl_xor(m, mk, 64));
        float p = __expf(lg - m);
        float s = p;
#pragma unroll
        for (int mk = 16; mk >= 1; mk >>= 1) s += __shfl_xor(s, mk, 64);
        coef[j] = p * __builtin_amdgcn_rcpf(s);
      }
    } else {
#pragma unroll
      for (int j = 0; j < 4; ++j) coef[j] = (1.0f / C_);
    }

#pragma unroll
    for (int j = 0; j < 4; ++j)
#pragma unroll
      for (int e = 0; e < 8; ++e) acc[j][e] = fmaf(coef[j], uh[j][e], acc[j][e]);
  }

  // write partial s for this i-chunk: [NIC][B][C][E]
#pragma unroll
  for (int j = 0; j < 4; ++j) {
    size_t base = ((size_t)blockIdx.x * B_ + (b0 + bq*4 + j)) * (C_*E_) + (size_t)c*E_ + eh*8;
    float4 o0 = {acc[j][0],acc[j][1],acc[j][2],acc[j][3]};
    float4 o1 = {acc[j][4],acc[j][5],acc[j][6],acc[j][7]};
    *(float4*)(partial + base)     = o0;
    *(float4*)(partial + base + 4) = o1;
  }
}

// Sum partials over NIC chunks -> s[b,c,e]; squash over e (16-lane groups);
// mode 0: vacc_out = v ; mode 1: vacc_out = vacc_in + v ; mode 2: vout = v
__global__ __launch_bounds__(256)
void reduce_squash(const float* __restrict__ partial,
                   const float* __restrict__ vacc_in, float* __restrict__ vacc_out,
                   float* __restrict__ vout, int mode)
{
  const int idx = blockIdx.x * 256 + threadIdx.x;   // 0..32767
  float s = 0.f;
#pragma unroll 8
  for (int k = 0; k < NIC_; ++k) s += partial[(size_t)k * (B_*C_*E_) + idx];
  float sq = s * s;
  sq += __shfl_xor(sq, 1); sq += __shfl_xor(sq, 2);
  sq += __shfl_xor(sq, 4); sq += __shfl_xor(sq, 8);
  float scale = sq / (1.f + sq) / (sqrtf(sq) + 1e-8f);
  float v = scale * s;
  if (mode == 0)      vacc_out[idx] = v;
  else if (mode == 1) vacc_out[idx] = vacc_in[idx] + v;
  else                vout[idx] = v;
}

extern "C" void kernel_launch(void* const* d_in, const int* in_sizes, int n_in,
                              void* d_out, int out_size, void* d_ws, size_t ws_size,
                              hipStream_t stream)
{
  const float* x = (const float*)d_in[0];
  const float* W = (const float*)d_in[1];
  float* out     = (float*)d_out;

  float* partial = (float*)d_ws;                          // NIC_*B*C*E f32 (9.4MB)
  float* vacc    = partial + (size_t)NIC_ * (B_*C_*E_);   // B*C*E f32 (128KB)

  dim3 pg(NIC_, B_/BC_);
  const int rblocks = (B_*C_*E_) / 256;                   // 128

  // iter 0: uniform coefficients (softmax of zeros = 1/32)
  caps_pass<false><<<pg, 256, 0, stream>>>(x, W, nullptr, partial);
  reduce_squash<<<rblocks, 256, 0, stream>>>(partial, nullptr, vacc, nullptr, 0);
  // iter 1: logits = u_hat . v0
  caps_pass<true><<<pg, 256, 0, stream>>>(x, W, vacc, partial);
  reduce_squash<<<rblocks, 256, 0, stream>>>(partial, vacc, vacc, nullptr, 1);
  // iter 2: logits = u_hat . (v0+v1)
  caps_pass<true><<<pg, 256, 0, stream>>>(x, W, vacc, partial);
  reduce_squash<<<rblocks, 256, 0, stream>>>(partial, nullptr, nullptr, out, 2);
}